// Round 1
// baseline (548.956 us; speedup 1.0000x reference)
//
#include <hip/hip_runtime.h>
#include <math.h>

#define EPS 1e-6f

#define B_   16
#define T_   2048
#define LD   256
#define NB   32
#define BT   (B_ * T_)          // 32768
#define NCH  32
#define CHUNK (T_ / NCH)        // 64

#define TM 64
#define TN 64
#define TK 16

// ---------------------------------------------------------------------------
// Precompute kernels
// ---------------------------------------------------------------------------

// dst[d][e] = src[e][d]  (256x256 transpose)
__global__ void k_transpose(const float* __restrict__ src, float* __restrict__ dst) {
    __shared__ float tile[32][33];
    int bx = blockIdx.x * 32, by = blockIdx.y * 32;
    int tx = threadIdx.x, ty = threadIdx.y;   // 32 x 8
    for (int j = 0; j < 32; j += 8)
        tile[ty + j][tx] = src[(by + ty + j) * LD + bx + tx];
    __syncthreads();
    for (int j = 0; j < 32; j += 8)
        dst[(bx + ty + j) * LD + by + tx] = tile[tx][ty + j];
}

// out[i][j] = sum_k E[k][i] * W[j][k]   (G_MT / G_CT: i=d, j=f, k=e)
__global__ void k_small_gemm(const float* __restrict__ E, const float* __restrict__ W,
                             float* __restrict__ out) {
    __shared__ float Es[16][17];   // Es[k][i]
    __shared__ float Ws[16][17];   // Ws[j][k]
    int tx = threadIdx.x, ty = threadIdx.y;   // 16x16
    int i0 = blockIdx.x * 16, j0 = blockIdx.y * 16;
    float acc = 0.f;
    for (int kb = 0; kb < LD; kb += 16) {
        Es[ty][tx] = E[(kb + ty) * LD + i0 + tx];
        Ws[ty][tx] = W[(j0 + ty) * LD + kb + tx];
        __syncthreads();
#pragma unroll
        for (int k = 0; k < 16; ++k)
            acc = fmaf(Es[k][ty], Ws[tx][k], acc);
        __syncthreads();
    }
    out[(i0 + ty) * LD + j0 + tx] = acc;
}

// block 0: im0,iv0,yv vectors.  blocks 1..32: A_basis rows.
__global__ void k_vec_pre(const float* __restrict__ E, const float* __restrict__ imp,
                          const float* __restrict__ ilv, const float* __restrict__ ylv,
                          const float* __restrict__ Dm,
                          float* __restrict__ im0, float* __restrict__ iv0,
                          float* __restrict__ yv, float* __restrict__ Ab) {
    int t = threadIdx.x;
    if (blockIdx.x == 0) {
        float sm = 0.f, sv = 0.f;
        for (int k = 0; k < LD; ++k) {
            float e = E[k * LD + t];
            sm = fmaf(e, imp[k], sm);
            sv = fmaf(e * e, expf(ilv[k]) + EPS, sv);
        }
        im0[t] = sm;
        iv0[t] = sv;
        yv[t]  = expf(ylv[t]) + EPS;
    } else {
        int n = blockIdx.x - 1;
        Ab[n * LD + t] = -(expf(Dm[n * LD + t]) + EPS);
    }
}

// ---------------------------------------------------------------------------
// K1: alphas = Z @ B_w^T   (32768x256 @ 256x256), BwT is [k][n]
// ---------------------------------------------------------------------------
__global__ __launch_bounds__(256) void k_alphas(const float* __restrict__ Z,
                                                const float* __restrict__ BwT,
                                                float* __restrict__ alphas) {
    __shared__ float As[TK][TM + 4];   // [k][m]
    __shared__ float Bs[TK][TN + 4];   // [k][n]
    int tid = threadIdx.x;
    int m0 = blockIdx.x * TM;
    int n0 = blockIdx.y * TN;
    int tn = tid & 15, tm = tid >> 4;
    int sr = tid >> 2;            // staging row 0..63
    int sc = (tid & 3) * 4;       // staging k group
    int kr = tid >> 4;            // B staging k 0..15
    int nc = (tid & 15) * 4;      // B staging n
    float acc[4][4] = {};
    for (int kb = 0; kb < LD; kb += TK) {
        float4 a4 = *(const float4*)&Z[(m0 + sr) * LD + kb + sc];
        As[sc + 0][sr] = a4.x; As[sc + 1][sr] = a4.y;
        As[sc + 2][sr] = a4.z; As[sc + 3][sr] = a4.w;
        *(float4*)&Bs[kr][nc] = *(const float4*)&BwT[(kb + kr) * LD + n0 + nc];
        __syncthreads();
#pragma unroll
        for (int k = 0; k < TK; ++k) {
            float4 af = *(const float4*)&As[k][tm * 4];
            float4 bf = *(const float4*)&Bs[k][tn * 4];
            float am[4] = {af.x, af.y, af.z, af.w};
            float bn[4] = {bf.x, bf.y, bf.z, bf.w};
#pragma unroll
            for (int i = 0; i < 4; ++i)
#pragma unroll
                for (int j = 0; j < 4; ++j)
                    acc[i][j] = fmaf(am[i], bn[j], acc[i][j]);
        }
        __syncthreads();
    }
#pragma unroll
    for (int i = 0; i < 4; ++i) {
        float4 o = make_float4(acc[i][0], acc[i][1], acc[i][2], acc[i][3]);
        *(float4*)&alphas[(m0 + tm * 4 + i) * LD + n0 + tn * 4] = o;
    }
}

// ---------------------------------------------------------------------------
// K1b: per-(b,t) map: logits -> softmax -> A_mat -> exp streams
// ---------------------------------------------------------------------------
__global__ __launch_bounds__(256) void k_map(const float* __restrict__ alphas,
                                             const float* __restrict__ cw,
                                             const float* __restrict__ cb,
                                             const float* __restrict__ Ab,
                                             const float* __restrict__ obs,
                                             float* __restrict__ SAm,
                                             float* __restrict__ SBm,
                                             float* __restrict__ SBv) {
    __shared__ float als[LD];
    __shared__ float red[NB][9];
    __shared__ float ac[NB];
    int bt  = blockIdx.x;
    int tid = threadIdx.x;
    float a_own = alphas[bt * LD + tid];
    als[tid] = a_own;
    __syncthreads();
    int n = tid >> 3, seg = tid & 7;
    float p = 0.f;
#pragma unroll
    for (int j = 0; j < 32; ++j) {
        int e = seg + 8 * j;                    // stride-8: conflict-free LDS banks
        p = fmaf(als[e], cw[n * LD + e], p);
    }
    red[n][seg] = p;
    __syncthreads();
    if (tid < NB) {
        float lg = cb[tid];
#pragma unroll
        for (int s = 0; s < 8; ++s) lg += red[tid][s];
        float mx = lg;
#pragma unroll
        for (int off = 16; off >= 1; off >>= 1) mx = fmaxf(mx, __shfl_xor(mx, off, 32));
        float e = expf(lg - mx);
        float sm = e;
#pragma unroll
        for (int off = 16; off >= 1; off >>= 1) sm += __shfl_xor(sm, off, 32);
        ac[tid] = e / sm;
    }
    __syncthreads();
    float Am = 0.f;
#pragma unroll
    for (int n2 = 0; n2 < NB; ++n2) Am = fmaf(ac[n2], Ab[n2 * LD + tid], Am);
    float t   = obs[bt];
    float eAm = expf(Am * t);
    float ieA = 1.f / Am;                       // A_mat < 0 always, |A| >= ~0.02
    float eBm = (eAm - 1.f) * ieA * a_own;
    float eBv = 0.5f * (eAm * eAm - 1.f) * ieA + EPS;
    int idx = bt * LD + tid;
    SAm[idx] = eAm;
    SBm[idx] = eBm;
    SBv[idx] = eBv;
}

// ---------------------------------------------------------------------------
// K2a: in-place local (per-chunk) scans.  One thread per (b, chunk, d),
// both mean and var recurrences (var A-value derived as la*la).
// ---------------------------------------------------------------------------
__global__ __launch_bounds__(256) void k_scan(float* __restrict__ SAm,
                                              float* __restrict__ SBm,
                                              float* __restrict__ SBv,
                                              float* __restrict__ totA,
                                              float* __restrict__ totBm,
                                              float* __restrict__ totBv) {
    int d  = threadIdx.x;
    int b  = blockIdx.x / NCH;
    int ch = blockIdx.x % NCH;
    int base = (b * T_ + ch * CHUNK) * LD + d;
    float ra = 1.f, rm = 0.f, rv = 0.f;
    float la = SAm[base], bm = SBm[base], bv = SBv[base];
#pragma unroll 4
    for (int i = 0; i < CHUNK; ++i) {
        int idx = base + i * LD;
        int nxt = (i < CHUNK - 1) ? LD : 0;
        float nla = SAm[idx + nxt];
        float nbm = SBm[idx + nxt];
        float nbv = SBv[idx + nxt];
        rm = fmaf(la, rm, bm);
        rv = fmaf(la * la, rv, bv);
        ra = la * ra;
        SAm[idx] = ra; SBm[idx] = rm; SBv[idx] = rv;
        la = nla; bm = nbm; bv = nbv;
    }
    int pidx = (b * NCH + ch) * LD + d;
    totA[pidx] = ra; totBm[pidx] = rm; totBv[pidx] = rv;
}

// K2b: exclusive prefix over chunks per (b,d)
__global__ void k_chunkpfx(const float* __restrict__ totA, const float* __restrict__ totBm,
                           const float* __restrict__ totBv,
                           float* __restrict__ preA, float* __restrict__ preBm,
                           float* __restrict__ preBv) {
    int d = threadIdx.x;
    int b = blockIdx.x;
    float Pa = 1.f, Pm = 0.f, Pv = 0.f;
    for (int ch = 0; ch < NCH; ++ch) {
        int pidx = (b * NCH + ch) * LD + d;
        preA[pidx] = Pa; preBm[pidx] = Pm; preBv[pidx] = Pv;
        float a = totA[pidx], tm_ = totBm[pidx], tv = totBv[pidx];
        Pm = fmaf(a, Pm, tm_);
        Pv = fmaf(a * a, Pv, tv);
        Pa = a * Pa;
    }
}

// ---------------------------------------------------------------------------
// K3: apply chunk prefixes -> m,s on the fly; means = [m|Z]@[G_M|G_C]^T,
// stds = s@G_M^T.  B-tile (G_MT) shared between means and stds accumulators.
// ---------------------------------------------------------------------------
__global__ __launch_bounds__(256) void k_out(const float* __restrict__ SAm,
                                             const float* __restrict__ SBm,
                                             const float* __restrict__ SBv,
                                             const float* __restrict__ preA,
                                             const float* __restrict__ preBm,
                                             const float* __restrict__ preBv,
                                             const float* __restrict__ GMT,
                                             const float* __restrict__ GCT,
                                             const float* __restrict__ Z,
                                             const float* __restrict__ im0,
                                             const float* __restrict__ iv0,
                                             const float* __restrict__ yv,
                                             float* __restrict__ means,
                                             float* __restrict__ stds) {
    __shared__ float Ms[TK][TM + 4];
    __shared__ float Ss[TK][TM + 4];
    __shared__ float Bs[TK][TN + 4];
    int tid = threadIdx.x;
    int m0 = blockIdx.x * TM;
    int n0 = blockIdx.y * TN;
    int tn = tid & 15, tm = tid >> 4;
    int sr = tid >> 2;
    int sc = (tid & 3) * 4;
    int kr = tid >> 4;
    int nc = (tid & 15) * 4;
    int grow = m0 + sr;                       // global bt row this thread stages
    int bb   = grow >> 11;                    // / T_
    int ch   = (grow >> 6) & (NCH - 1);       // / CHUNK within b
    int pbase = (bb * NCH + ch) * LD;
    float accm[4][4] = {};
    float accs[4][4] = {};

    // phase 1: k in [0,256): A-tiles = m and s (computed in staging), B = G_MT
    for (int kb = 0; kb < LD; kb += TK) {
        float4 l4 = *(const float4*)&SAm[grow * LD + kb + sc];
        float4 m4 = *(const float4*)&SBm[grow * LD + kb + sc];
        float4 v4 = *(const float4*)&SBv[grow * LD + kb + sc];
        float4 pa4 = *(const float4*)&preA[pbase + kb + sc];
        float4 pm4 = *(const float4*)&preBm[pbase + kb + sc];
        float4 pv4 = *(const float4*)&preBv[pbase + kb + sc];
        float4 i4 = *(const float4*)&im0[kb + sc];
        float4 w4 = *(const float4*)&iv0[kb + sc];
        float4 y4 = *(const float4*)&yv[kb + sc];
#define APPLY(c, j)                                                     \
        {                                                               \
            float la = l4.c;                                            \
            float cA = la * pa4.c;                                      \
            float cBm = fmaf(la, pm4.c, m4.c);                          \
            float cBv = fmaf(la * la, pv4.c, v4.c);                     \
            float mm = fmaf(cA, i4.c, cBm);                             \
            float vv = fmaf(cA * cA, w4.c, cBv) + y4.c;                 \
            Ms[sc + j][sr] = mm;                                        \
            Ss[sc + j][sr] = sqrtf(vv);                                 \
        }
        APPLY(x, 0) APPLY(y, 1) APPLY(z, 2) APPLY(w, 3)
#undef APPLY
        *(float4*)&Bs[kr][nc] = *(const float4*)&GMT[(kb + kr) * LD + n0 + nc];
        __syncthreads();
#pragma unroll
        for (int k = 0; k < TK; ++k) {
            float4 mf = *(const float4*)&Ms[k][tm * 4];
            float4 sf = *(const float4*)&Ss[k][tm * 4];
            float4 bf = *(const float4*)&Bs[k][tn * 4];
            float mi[4] = {mf.x, mf.y, mf.z, mf.w};
            float si[4] = {sf.x, sf.y, sf.z, sf.w};
            float bn[4] = {bf.x, bf.y, bf.z, bf.w};
#pragma unroll
            for (int i = 0; i < 4; ++i)
#pragma unroll
                for (int j = 0; j < 4; ++j) {
                    accm[i][j] = fmaf(mi[i], bn[j], accm[i][j]);
                    accs[i][j] = fmaf(si[i], bn[j], accs[i][j]);
                }
        }
        __syncthreads();
    }

    // phase 2: history: A = Z, B = G_CT (means only)
    for (int kb = 0; kb < LD; kb += TK) {
        float4 z4 = *(const float4*)&Z[grow * LD + kb + sc];
        Ms[sc + 0][sr] = z4.x; Ms[sc + 1][sr] = z4.y;
        Ms[sc + 2][sr] = z4.z; Ms[sc + 3][sr] = z4.w;
        *(float4*)&Bs[kr][nc] = *(const float4*)&GCT[(kb + kr) * LD + n0 + nc];
        __syncthreads();
#pragma unroll
        for (int k = 0; k < TK; ++k) {
            float4 mf = *(const float4*)&Ms[k][tm * 4];
            float4 bf = *(const float4*)&Bs[k][tn * 4];
            float mi[4] = {mf.x, mf.y, mf.z, mf.w};
            float bn[4] = {bf.x, bf.y, bf.z, bf.w};
#pragma unroll
            for (int i = 0; i < 4; ++i)
#pragma unroll
                for (int j = 0; j < 4; ++j)
                    accm[i][j] = fmaf(mi[i], bn[j], accm[i][j]);
        }
        __syncthreads();
    }

#pragma unroll
    for (int i = 0; i < 4; ++i) {
        int row = m0 + tm * 4 + i;
        float4 om = make_float4(accm[i][0], accm[i][1], accm[i][2], accm[i][3]);
        float4 os = make_float4(accs[i][0], accs[i][1], accs[i][2], accs[i][3]);
        *(float4*)&means[row * LD + n0 + tn * 4] = om;
        *(float4*)&stds [row * LD + n0 + tn * 4] = os;
    }
}

// ---------------------------------------------------------------------------
extern "C" void kernel_launch(void* const* d_in, const int* in_sizes, int n_in,
                              void* d_out, int out_size, void* d_ws, size_t ws_size,
                              hipStream_t stream) {
    const float* Z   = (const float*)d_in[0];
    const float* obs = (const float*)d_in[1];
    const float* Dm  = (const float*)d_in[2];
    const float* cw  = (const float*)d_in[3];
    const float* cb  = (const float*)d_in[4];
    const float* Ew  = (const float*)d_in[5];
    const float* Bw  = (const float*)d_in[6];
    const float* Cw  = (const float*)d_in[7];
    const float* Mw  = (const float*)d_in[8];
    const float* imp = (const float*)d_in[9];
    const float* ilv = (const float*)d_in[10];
    const float* ylv = (const float*)d_in[11];

    float* out    = (float*)d_out;
    float* means  = out;
    float* stds   = out + (size_t)BT * LD;
    float* alphas = out + (size_t)2 * BT * LD;

    float* ws = (float*)d_ws;
    size_t o = 0;
    float* SAm   = ws + o; o += (size_t)BT * LD;       // 8388608
    float* SBm   = ws + o; o += (size_t)BT * LD;
    float* SBv   = ws + o; o += (size_t)BT * LD;
    float* totA  = ws + o; o += (size_t)B_ * NCH * LD; // 131072
    float* totBm = ws + o; o += (size_t)B_ * NCH * LD;
    float* totBv = ws + o; o += (size_t)B_ * NCH * LD;
    float* preA  = ws + o; o += (size_t)B_ * NCH * LD;
    float* preBm = ws + o; o += (size_t)B_ * NCH * LD;
    float* preBv = ws + o; o += (size_t)B_ * NCH * LD;
    float* BwT   = ws + o; o += (size_t)LD * LD;
    float* GMT   = ws + o; o += (size_t)LD * LD;
    float* GCT   = ws + o; o += (size_t)LD * LD;
    float* Ab    = ws + o; o += (size_t)NB * LD;
    float* im0   = ws + o; o += LD;
    float* iv0   = ws + o; o += LD;
    float* yv    = ws + o; o += LD;

    // precompute
    k_transpose<<<dim3(8, 8), dim3(32, 8), 0, stream>>>(Bw, BwT);
    k_small_gemm<<<dim3(16, 16), dim3(16, 16), 0, stream>>>(Ew, Mw, GMT);
    k_small_gemm<<<dim3(16, 16), dim3(16, 16), 0, stream>>>(Ew, Cw, GCT);
    k_vec_pre<<<dim3(33), dim3(LD), 0, stream>>>(Ew, imp, ilv, ylv, Dm, im0, iv0, yv, Ab);

    // main pipeline
    k_alphas<<<dim3(BT / TM, LD / TN), dim3(256), 0, stream>>>(Z, BwT, alphas);
    k_map<<<dim3(BT), dim3(256), 0, stream>>>(alphas, cw, cb, Ab, obs, SAm, SBm, SBv);
    k_scan<<<dim3(B_ * NCH), dim3(LD), 0, stream>>>(SAm, SBm, SBv, totA, totBm, totBv);
    k_chunkpfx<<<dim3(B_), dim3(LD), 0, stream>>>(totA, totBm, totBv, preA, preBm, preBv);
    k_out<<<dim3(BT / TM, LD / TN), dim3(256), 0, stream>>>(SAm, SBm, SBv, preA, preBm, preBv,
                                                            GMT, GCT, Z, im0, iv0, yv,
                                                            means, stds);
}

// Round 2
// 288.939 us; speedup vs baseline: 1.8999x; 1.8999x over previous
//
#include <hip/hip_runtime.h>
#include <math.h>

#define EPS 1e-6f

#define B_   16
#define T_   2048
#define LD   256
#define NB   32
#define BT   (B_ * T_)          // 32768
#define NCH  32
#define CHUNK (T_ / NCH)        // 64

typedef short bf16x8 __attribute__((ext_vector_type(8)));
typedef float f32x4  __attribute__((ext_vector_type(4)));

__device__ __forceinline__ unsigned short f2b(float f) {
    unsigned int u = __float_as_uint(f);
    unsigned int r = (u + 0x7fffu + ((u >> 16) & 1u)) >> 16;
    return (unsigned short)r;
}

__device__ __forceinline__ void gl_lds16(const void* g, void* l) {
    __builtin_amdgcn_global_load_lds(
        (const __attribute__((address_space(1))) unsigned int*)g,
        (__attribute__((address_space(3))) unsigned int*)l, 16, 0, 0);
}

// Stage a 128-row x 32-col bf16 tile into LDS [128][32] with quad swizzle:
// physical quad p at row r holds logical quad qd = p ^ ((r>>1)&3).
__device__ __forceinline__ void stage_tile(const unsigned short* __restrict__ src,
                                           int row0, int stride, int kb,
                                           unsigned short* lds, int wv, int lane) {
#pragma unroll
    for (int cc = 0; cc < 2; ++cc) {
        int c = wv * 2 + cc;                 // chunk 0..7, 16 rows each
        int r = c * 16 + (lane >> 2);
        int qd = (lane & 3) ^ ((r >> 1) & 3);
        const unsigned short* g = src + (size_t)(row0 + r) * stride + kb + qd * 8;
        gl_lds16(g, lds + c * 512);          // wave-uniform LDS base; HW adds lane*16B
    }
}

__device__ __forceinline__ bf16x8 frag_ld(const unsigned short* lds, int row, int qd) {
    int pq = qd ^ ((row >> 1) & 3);
    return *(const bf16x8*)(lds + row * 32 + pq * 8);
}

// ---------------------------------------------------------------------------
// Generic 128x128-tile bf16 MFMA GEMM: C[M][N] = A[M][K]*Bt[N][K]^T, fp32 out.
// KLEN = K per half (also row stride of each source), HALVES in {1,2},
// DUAL=1 also writes bf16 copy to C2.  Grid: (M/128, N/128), 256 threads.
// ---------------------------------------------------------------------------
template<int KLEN, int HALVES, int DUAL>
__global__ __launch_bounds__(256) void k_gemm128(const unsigned short* __restrict__ A0,
                                                 const unsigned short* __restrict__ A1,
                                                 const unsigned short* __restrict__ B0,
                                                 const unsigned short* __restrict__ B1,
                                                 float* __restrict__ C,
                                                 unsigned short* __restrict__ C2,
                                                 int nout) {
    __shared__ unsigned short As[128 * 32];
    __shared__ unsigned short Bs[128 * 32];
    int tid = threadIdx.x, lane = tid & 63, wv = tid >> 6;
    int m0 = blockIdx.x * 128, n0 = blockIdx.y * 128;
    int wm = (wv & 1) * 64, wn = (wv >> 1) * 64;
    f32x4 acc[4][4];
#pragma unroll
    for (int i = 0; i < 4; ++i)
#pragma unroll
        for (int j = 0; j < 4; ++j) acc[i][j] = (f32x4){0.f, 0.f, 0.f, 0.f};

    for (int h = 0; h < HALVES; ++h) {
        const unsigned short* A = h ? A1 : A0;
        const unsigned short* B = h ? B1 : B0;
        for (int kb = 0; kb < KLEN; kb += 32) {
            stage_tile(A, m0, KLEN, kb, As, wv, lane);
            stage_tile(B, n0, KLEN, kb, Bs, wv, lane);
            __syncthreads();
            int qd = lane >> 4;
            bf16x8 af[4], bf[4];
#pragma unroll
            for (int i = 0; i < 4; ++i) af[i] = frag_ld(As, wm + i * 16 + (lane & 15), qd);
#pragma unroll
            for (int j = 0; j < 4; ++j) bf[j] = frag_ld(Bs, wn + j * 16 + (lane & 15), qd);
#pragma unroll
            for (int i = 0; i < 4; ++i)
#pragma unroll
                for (int j = 0; j < 4; ++j)
                    acc[i][j] = __builtin_amdgcn_mfma_f32_16x16x32_bf16(af[i], bf[j], acc[i][j], 0, 0, 0);
            __syncthreads();
        }
    }
    int col = wn + (lane & 15);
    int rb  = wm + ((lane >> 4) << 2);
#pragma unroll
    for (int i = 0; i < 4; ++i)
#pragma unroll
        for (int j = 0; j < 4; ++j)
#pragma unroll
            for (int r = 0; r < 4; ++r) {
                int row = m0 + rb + i * 16 + r;
                int cc  = n0 + col + j * 16;
                float v = acc[i][j][r];
                C[(size_t)row * nout + cc] = v;
                if (DUAL) C2[(size_t)row * nout + cc] = f2b(v);
            }
}

// ---------------------------------------------------------------------------
// Logits GEMM: C[M][32] = A[M][256]*Bt[32][256]^T + bias.  Grid (M/128).
// ---------------------------------------------------------------------------
__global__ __launch_bounds__(256) void k_gemm_logits(const unsigned short* __restrict__ A,
                                                     const unsigned short* __restrict__ B,
                                                     const float* __restrict__ bias,
                                                     float* __restrict__ C) {
    __shared__ unsigned short As[128 * 32];
    __shared__ unsigned short Bs2[32 * 32];
    int tid = threadIdx.x, lane = tid & 63, wv = tid >> 6;
    int m0 = blockIdx.x * 128;
    f32x4 acc[2][2];
#pragma unroll
    for (int i = 0; i < 2; ++i)
#pragma unroll
        for (int j = 0; j < 2; ++j) acc[i][j] = (f32x4){0.f, 0.f, 0.f, 0.f};

    for (int kb = 0; kb < 256; kb += 32) {
        stage_tile(A, m0, 256, kb, As, wv, lane);
        if (wv < 2) {
            int r = wv * 16 + (lane >> 2);
            int qd = (lane & 3) ^ ((r >> 1) & 3);
            gl_lds16(B + (size_t)r * 256 + kb + qd * 8, Bs2 + wv * 512);
        }
        __syncthreads();
        int qd = lane >> 4;
        bf16x8 af[2], bff[2];
#pragma unroll
        for (int i = 0; i < 2; ++i) af[i] = frag_ld(As, wv * 32 + i * 16 + (lane & 15), qd);
#pragma unroll
        for (int j = 0; j < 2; ++j) bff[j] = frag_ld(Bs2, j * 16 + (lane & 15), qd);
#pragma unroll
        for (int i = 0; i < 2; ++i)
#pragma unroll
            for (int j = 0; j < 2; ++j)
                acc[i][j] = __builtin_amdgcn_mfma_f32_16x16x32_bf16(af[i], bff[j], acc[i][j], 0, 0, 0);
        __syncthreads();
    }
    int col = lane & 15;
    int rb  = (lane >> 4) << 2;
#pragma unroll
    for (int i = 0; i < 2; ++i)
#pragma unroll
        for (int j = 0; j < 2; ++j)
#pragma unroll
            for (int r = 0; r < 4; ++r) {
                int row = m0 + wv * 32 + i * 16 + rb + r;
                int cc  = j * 16 + col;
                C[(size_t)row * NB + cc] = acc[i][j][r] + bias[cc];
            }
}

// ---------------------------------------------------------------------------
// Elementwise / small kernels
// ---------------------------------------------------------------------------
__global__ void k_cast(const float* __restrict__ src, unsigned short* __restrict__ dst, int n4) {
    int i = blockIdx.x * blockDim.x + threadIdx.x;
    if (i < n4) {
        float4 v = ((const float4*)src)[i];
        ushort4 o = make_ushort4(f2b(v.x), f2b(v.y), f2b(v.z), f2b(v.w));
        ((ushort4*)dst)[i] = o;
    }
}

// out[f][d] = sum_e W[f][e] * E[e][d], bf16 out  (G_M = M_w@E_w, G_C = C_w@E_w)
__global__ void k_small_gemm(const float* __restrict__ E, const float* __restrict__ W,
                             unsigned short* __restrict__ out) {
    __shared__ float Ws[16][17];
    __shared__ float Es[16][17];
    int tx = threadIdx.x, ty = threadIdx.y;
    int d0 = blockIdx.x * 16, f0 = blockIdx.y * 16;
    float acc = 0.f;
    for (int eb = 0; eb < LD; eb += 16) {
        Ws[ty][tx] = W[(f0 + ty) * LD + eb + tx];
        Es[ty][tx] = E[(eb + ty) * LD + d0 + tx];
        __syncthreads();
#pragma unroll
        for (int k = 0; k < 16; ++k) acc = fmaf(Ws[ty][k], Es[k][tx], acc);
        __syncthreads();
    }
    out[(f0 + ty) * LD + d0 + tx] = f2b(acc);
}

// block 0: im0,iv0,yv.  blocks 1..32: AbT[d][n] = bf16(-(exp(D[n][d])+EPS))
__global__ void k_vec_pre(const float* __restrict__ E, const float* __restrict__ imp,
                          const float* __restrict__ ilv, const float* __restrict__ ylv,
                          const float* __restrict__ Dm,
                          float* __restrict__ im0, float* __restrict__ iv0,
                          float* __restrict__ yv, unsigned short* __restrict__ AbT) {
    int t = threadIdx.x;
    if (blockIdx.x == 0) {
        float sm = 0.f, sv = 0.f;
        for (int k = 0; k < LD; ++k) {
            float e = E[k * LD + t];
            sm = fmaf(e, imp[k], sm);
            sv = fmaf(e * e, expf(ilv[k]) + EPS, sv);
        }
        im0[t] = sm;
        iv0[t] = sv;
        yv[t]  = expf(ylv[t]) + EPS;
    } else {
        int n = blockIdx.x - 1;
        AbT[t * NB + n] = f2b(-(expf(Dm[n * LD + t]) + EPS));
    }
}

// softmax over 32 logits per row -> bf16
__global__ __launch_bounds__(256) void k_soft(const float* __restrict__ logits,
                                              unsigned short* __restrict__ ach) {
    int tid = threadIdx.x;
    int row = blockIdx.x * 8 + (tid >> 5);
    int l = tid & 31;
    float v = logits[(size_t)row * NB + l];
    float mx = v;
#pragma unroll
    for (int off = 16; off >= 1; off >>= 1) mx = fmaxf(mx, __shfl_xor(mx, off, 32));
    float e = expf(v - mx);
    float s = e;
#pragma unroll
    for (int off = 16; off >= 1; off >>= 1) s += __shfl_xor(s, off, 32);
    ach[(size_t)row * NB + l] = f2b(e / s);
}

// ---------------------------------------------------------------------------
// Pass 1: chunk totals only (recompute emap on the fly, nothing stored)
// ---------------------------------------------------------------------------
__global__ __launch_bounds__(256) void k_tot(const float* __restrict__ Amat,
                                             const float* __restrict__ alphas,
                                             const float* __restrict__ obs,
                                             float* __restrict__ totA,
                                             float* __restrict__ totBm,
                                             float* __restrict__ totBv) {
    int d = threadIdx.x;
    int b = blockIdx.x >> 5, ch = blockIdx.x & 31;
    int bt0 = b * T_ + ch * CHUNK;
    float ra = 1.f, rm = 0.f, rv = 0.f;
    for (int i = 0; i < CHUNK; ++i) {
        size_t idx = (size_t)(bt0 + i) * LD + d;
        float Am = Amat[idx];
        float av = alphas[idx];
        float tt = obs[bt0 + i];
        float eAm = expf(Am * tt);
        float ieA = 1.f / Am;
        float eBm = (eAm - 1.f) * ieA * av;
        float eBv = 0.5f * (eAm * eAm - 1.f) * ieA + EPS;
        rm = fmaf(eAm, rm, eBm);
        rv = fmaf(eAm * eAm, rv, eBv);
        ra *= eAm;
    }
    int pidx = blockIdx.x * LD + d;
    totA[pidx] = ra; totBm[pidx] = rm; totBv[pidx] = rv;
}

// exclusive prefix over chunks per (b,d)
__global__ void k_chunkpfx(const float* __restrict__ totA, const float* __restrict__ totBm,
                           const float* __restrict__ totBv,
                           float* __restrict__ preA, float* __restrict__ preBm,
                           float* __restrict__ preBv) {
    int d = threadIdx.x;
    int b = blockIdx.x;
    float Pa = 1.f, Pm = 0.f, Pv = 0.f;
    for (int ch = 0; ch < NCH; ++ch) {
        int pidx = (b * NCH + ch) * LD + d;
        preA[pidx] = Pa; preBm[pidx] = Pm; preBv[pidx] = Pv;
        float a = totA[pidx], tm_ = totBm[pidx], tv = totBv[pidx];
        Pm = fmaf(a, Pm, tm_);
        Pv = fmaf(a * a, Pv, tv);
        Pa = a * Pa;
    }
}

// ---------------------------------------------------------------------------
// Pass 2: recompute emap, run prefix-composed scan, emit bf16 m and s directly
// ---------------------------------------------------------------------------
__global__ __launch_bounds__(256) void k_scan_apply(const float* __restrict__ Amat,
                                                    const float* __restrict__ alphas,
                                                    const float* __restrict__ obs,
                                                    const float* __restrict__ preA,
                                                    const float* __restrict__ preBm,
                                                    const float* __restrict__ preBv,
                                                    const float* __restrict__ im0,
                                                    const float* __restrict__ iv0,
                                                    const float* __restrict__ yv,
                                                    unsigned short* __restrict__ Mh,
                                                    unsigned short* __restrict__ Sh) {
    int d = threadIdx.x;
    int b = blockIdx.x >> 5, ch = blockIdx.x & 31;
    int bt0 = b * T_ + ch * CHUNK;
    int pidx = blockIdx.x * LD + d;
    float ga = preA[pidx], gm = preBm[pidx], gv = preBv[pidx];
    float i0 = im0[d], v0 = iv0[d], yvd = yv[d];
    for (int i = 0; i < CHUNK; ++i) {
        size_t idx = (size_t)(bt0 + i) * LD + d;
        float Am = Amat[idx];
        float av = alphas[idx];
        float tt = obs[bt0 + i];
        float eAm = expf(Am * tt);
        float ieA = 1.f / Am;
        float eBm = (eAm - 1.f) * ieA * av;
        float eBv = 0.5f * (eAm * eAm - 1.f) * ieA + EPS;
        gm = fmaf(eAm, gm, eBm);
        gv = fmaf(eAm * eAm, gv, eBv);
        ga *= eAm;
        float mm = fmaf(ga, i0, gm);
        float vv = fmaf(ga * ga, v0, gv) + yvd;
        Mh[idx] = f2b(mm);
        Sh[idx] = f2b(sqrtf(vv));
    }
}

// ---------------------------------------------------------------------------
extern "C" void kernel_launch(void* const* d_in, const int* in_sizes, int n_in,
                              void* d_out, int out_size, void* d_ws, size_t ws_size,
                              hipStream_t stream) {
    const float* Z   = (const float*)d_in[0];
    const float* obs = (const float*)d_in[1];
    const float* Dm  = (const float*)d_in[2];
    const float* cw  = (const float*)d_in[3];
    const float* cb  = (const float*)d_in[4];
    const float* Ew  = (const float*)d_in[5];
    const float* Bw  = (const float*)d_in[6];
    const float* Cw  = (const float*)d_in[7];
    const float* Mw  = (const float*)d_in[8];
    const float* imp = (const float*)d_in[9];
    const float* ilv = (const float*)d_in[10];
    const float* ylv = (const float*)d_in[11];

    float* out    = (float*)d_out;
    float* means  = out;
    float* stds   = out + (size_t)BT * LD;
    float* alphas = out + (size_t)2 * BT * LD;

    // Zh parks in the stds output region (written last)
    unsigned short* Zh = (unsigned short*)stds;

    char* ws = (char*)d_ws;
    size_t o = 0;
    float*          Amat = (float*)(ws + o);          o += (size_t)BT * LD * 4;   // 32MB
    unsigned short* Mh   = (unsigned short*)(ws + o); o += (size_t)BT * LD * 2;   // 16MB
    unsigned short* Sh   = (unsigned short*)(ws + o); o += (size_t)BT * LD * 2;   // 16MB
    unsigned short* ach  = (unsigned short*)(ws + o); o += (size_t)BT * NB * 2;   // 2MB
    unsigned short* GMh  = (unsigned short*)(ws + o); o += (size_t)LD * LD * 2;
    unsigned short* GCh  = (unsigned short*)(ws + o); o += (size_t)LD * LD * 2;
    unsigned short* Bwh  = (unsigned short*)(ws + o); o += (size_t)LD * LD * 2;
    unsigned short* cwh  = (unsigned short*)(ws + o); o += (size_t)NB * LD * 2;
    unsigned short* AbT  = (unsigned short*)(ws + o); o += (size_t)LD * NB * 2;
    float* totA  = (float*)(ws + o); o += (size_t)B_ * NCH * LD * 4;
    float* totBm = (float*)(ws + o); o += (size_t)B_ * NCH * LD * 4;
    float* totBv = (float*)(ws + o); o += (size_t)B_ * NCH * LD * 4;
    float* preA  = (float*)(ws + o); o += (size_t)B_ * NCH * LD * 4;
    float* preBm = (float*)(ws + o); o += (size_t)B_ * NCH * LD * 4;
    float* preBv = (float*)(ws + o); o += (size_t)B_ * NCH * LD * 4;
    float* im0   = (float*)(ws + o); o += LD * 4;
    float* iv0   = (float*)(ws + o); o += LD * 4;
    float* yv    = (float*)(ws + o); o += LD * 4;

    unsigned short* alphash = Mh;          // dead before Mh is written
    float*          logits  = (float*)Sh;  // 4MB, dead before Sh is written

    // --- precompute / casts ---
    k_cast<<<dim3((BT * LD / 4 + 255) / 256), dim3(256), 0, stream>>>(Z, Zh, BT * LD / 4);
    k_cast<<<dim3((LD * LD / 4 + 255) / 256), dim3(256), 0, stream>>>(Bw, Bwh, LD * LD / 4);
    k_cast<<<dim3((NB * LD / 4 + 255) / 256), dim3(256), 0, stream>>>(cw, cwh, NB * LD / 4);
    k_small_gemm<<<dim3(16, 16), dim3(16, 16), 0, stream>>>(Ew, Mw, GMh);
    k_small_gemm<<<dim3(16, 16), dim3(16, 16), 0, stream>>>(Ew, Cw, GCh);
    k_vec_pre<<<dim3(33), dim3(LD), 0, stream>>>(Ew, imp, ilv, ylv, Dm, im0, iv0, yv, AbT);

    // --- alphas (fp32 out + bf16 copy) ---
    k_gemm128<256, 1, 1><<<dim3(BT / 128, 2), dim3(256), 0, stream>>>(
        Zh, nullptr, Bwh, nullptr, alphas, alphash, LD);

    // --- logits -> softmax -> A_mat ---
    k_gemm_logits<<<dim3(BT / 128), dim3(256), 0, stream>>>(alphash, cwh, cb, logits);
    k_soft<<<dim3(BT / 8), dim3(256), 0, stream>>>(logits, ach);
    k_gemm128<32, 1, 0><<<dim3(BT / 128, 2), dim3(256), 0, stream>>>(
        ach, nullptr, AbT, nullptr, Amat, nullptr, LD);

    // --- scan (2-pass, nothing but totals materialized in fp32) ---
    k_tot<<<dim3(B_ * NCH), dim3(LD), 0, stream>>>(Amat, alphas, obs, totA, totBm, totBv);
    k_chunkpfx<<<dim3(B_), dim3(LD), 0, stream>>>(totA, totBm, totBv, preA, preBm, preBv);
    k_scan_apply<<<dim3(B_ * NCH), dim3(LD), 0, stream>>>(Amat, alphas, obs,
                                                          preA, preBm, preBv,
                                                          im0, iv0, yv, Mh, Sh);

    // --- output GEMMs (means first: it reads Zh which lives in stds region) ---
    k_gemm128<256, 2, 0><<<dim3(BT / 128, 2), dim3(256), 0, stream>>>(
        Mh, Zh, GMh, GCh, means, nullptr, LD);
    k_gemm128<256, 1, 0><<<dim3(BT / 128, 2), dim3(256), 0, stream>>>(
        Sh, nullptr, GMh, nullptr, stds, nullptr, LD);
}

// Round 3
// 249.278 us; speedup vs baseline: 2.2022x; 1.1591x over previous
//
#include <hip/hip_runtime.h>
#include <math.h>

#define EPS 1e-6f

#define B_   16
#define T_   2048
#define LD   256
#define NB   32
#define BT   (B_ * T_)          // 32768
#define NCH  32
#define CHUNK (T_ / NCH)        // 64

typedef short bf16x8 __attribute__((ext_vector_type(8)));
typedef float f32x4  __attribute__((ext_vector_type(4)));

__device__ __forceinline__ unsigned short f2b(float f) {
    unsigned int u = __float_as_uint(f);
    unsigned int r = (u + 0x7fffu + ((u >> 16) & 1u)) >> 16;
    return (unsigned short)r;
}

__device__ __forceinline__ void gl_lds16(const void* g, void* l) {
    __builtin_amdgcn_global_load_lds(
        (const __attribute__((address_space(1))) unsigned int*)g,
        (__attribute__((address_space(3))) unsigned int*)l, 16, 0, 0);
}

// Stage a 128-row x 32-col bf16 tile into LDS [128][32] with quad swizzle:
// physical quad p at row r holds logical quad qd = p ^ ((r>>1)&3).
__device__ __forceinline__ void stage_tile(const unsigned short* __restrict__ src,
                                           int row0, int stride, int kb,
                                           unsigned short* lds, int wv, int lane) {
#pragma unroll
    for (int cc = 0; cc < 2; ++cc) {
        int c = wv * 2 + cc;                 // chunk 0..7, 16 rows each
        int r = c * 16 + (lane >> 2);
        int qd = (lane & 3) ^ ((r >> 1) & 3);
        const unsigned short* g = src + (size_t)(row0 + r) * stride + kb + qd * 8;
        gl_lds16(g, lds + c * 512);          // wave-uniform LDS base; HW adds lane*16B
    }
}

__device__ __forceinline__ bf16x8 frag_ld(const unsigned short* lds, int row, int qd) {
    int pq = qd ^ ((row >> 1) & 3);
    return *(const bf16x8*)(lds + row * 32 + pq * 8);
}

// ---------------------------------------------------------------------------
// k_pre: ALL precompute in one launch, decoded by blockIdx.x (256 thr/block):
//   [0,256)    GMh[f][d]  = bf16( sum_e Mw[f][e]*Ew[e][d] )
//   [256,512)  GCh[f][d]  = bf16( sum_e Cw[f][e]*Ew[e][d] )
//   [512,544)  cwbh[n][d] = bf16( sum_e cw[n][e]*Bw[e][d] )
//   [544,577)  im0/iv0/yv (sub 0) and Ab rows (sub 1..32, fp32)
//   [577,641)  Bwh = bf16(Bw)
//   [641,8833) Zh  = bf16(Z)
// ---------------------------------------------------------------------------
__global__ __launch_bounds__(256) void k_pre(const float* __restrict__ Z,
                                             const float* __restrict__ Dm,
                                             const float* __restrict__ cw,
                                             const float* __restrict__ Ew,
                                             const float* __restrict__ Bw,
                                             const float* __restrict__ Cw,
                                             const float* __restrict__ Mw,
                                             const float* __restrict__ imp,
                                             const float* __restrict__ ilv,
                                             const float* __restrict__ ylv,
                                             unsigned short* __restrict__ GMh,
                                             unsigned short* __restrict__ GCh,
                                             unsigned short* __restrict__ cwbh,
                                             float* __restrict__ im0,
                                             float* __restrict__ iv0,
                                             float* __restrict__ yv,
                                             float* __restrict__ Ab,
                                             unsigned short* __restrict__ Bwh,
                                             unsigned short* __restrict__ Zh) {
    int bid = blockIdx.x;
    int tid = threadIdx.x;
    if (bid < 544) {
        // small GEMM: out[f][d] = sum_e W[f][e] * E[e][d]
        const float* W; const float* E; unsigned short* out; int d0, f0;
        if (bid < 256)      { W = Mw; E = Ew; out = GMh;  d0 = (bid & 15) * 16; f0 = (bid >> 4) * 16; }
        else if (bid < 512) { W = Cw; E = Ew; out = GCh;  d0 = (bid & 15) * 16; f0 = ((bid - 256) >> 4) * 16; }
        else                { W = cw; E = Bw; out = cwbh; d0 = (bid & 15) * 16; f0 = ((bid - 512) >> 4) * 16; }
        __shared__ float Ws[16][17];
        __shared__ float Es[16][17];
        int tx = tid & 15, ty = tid >> 4;
        float acc = 0.f;
        for (int eb = 0; eb < LD; eb += 16) {
            Ws[ty][tx] = W[(f0 + ty) * LD + eb + tx];
            Es[ty][tx] = E[(eb + ty) * LD + d0 + tx];
            __syncthreads();
#pragma unroll
            for (int k = 0; k < 16; ++k) acc = fmaf(Ws[ty][k], Es[k][tx], acc);
            __syncthreads();
        }
        out[(f0 + ty) * LD + d0 + tx] = f2b(acc);
    } else if (bid < 577) {
        int sub = bid - 544;
        int t = tid;
        if (sub == 0) {
            float sm = 0.f, sv = 0.f;
            for (int k = 0; k < LD; ++k) {
                float e = Ew[k * LD + t];
                sm = fmaf(e, imp[k], sm);
                sv = fmaf(e * e, expf(ilv[k]) + EPS, sv);
            }
            im0[t] = sm;
            iv0[t] = sv;
            yv[t]  = expf(ylv[t]) + EPS;
        } else {
            int n = sub - 1;
            Ab[n * LD + t] = -(expf(Dm[n * LD + t]) + EPS);
        }
    } else if (bid < 641) {
        int i = (bid - 577) * 256 + tid;      // float4 index over 256*256/4
        float4 v = ((const float4*)Bw)[i];
        ((ushort4*)Bwh)[i] = make_ushort4(f2b(v.x), f2b(v.y), f2b(v.z), f2b(v.w));
    } else {
        int i = (bid - 641) * 256 + tid;      // float4 index over BT*LD/4
        float4 v = ((const float4*)Z)[i];
        ((ushort4*)Zh)[i] = make_ushort4(f2b(v.x), f2b(v.y), f2b(v.z), f2b(v.w));
    }
}

// ---------------------------------------------------------------------------
// k_zb: grid (BT/128, 3).
//  y<2 : alphas[:,y*128:(y+1)*128] = Zh @ Bwh^T   (fp32 out)
//  y==2: logits = Zh @ cwbh^T + cb                (fp32 out, N=32)
// ---------------------------------------------------------------------------
__global__ __launch_bounds__(256) void k_zb(const unsigned short* __restrict__ Zh,
                                            const unsigned short* __restrict__ Bwh,
                                            const unsigned short* __restrict__ cwbh,
                                            const float* __restrict__ cb,
                                            float* __restrict__ alphas,
                                            float* __restrict__ logits) {
    __shared__ unsigned short As[128 * 32];
    __shared__ unsigned short Bs[128 * 32];
    int tid = threadIdx.x, lane = tid & 63, wv = tid >> 6;
    int m0 = blockIdx.x * 128;
    int y  = blockIdx.y;
    if (y < 2) {
        int n0 = y * 128;
        int wm = (wv & 1) * 64, wn = (wv >> 1) * 64;
        f32x4 acc[4][4];
#pragma unroll
        for (int i = 0; i < 4; ++i)
#pragma unroll
            for (int j = 0; j < 4; ++j) acc[i][j] = (f32x4){0.f, 0.f, 0.f, 0.f};
        for (int kb = 0; kb < LD; kb += 32) {
            stage_tile(Zh, m0, LD, kb, As, wv, lane);
            stage_tile(Bwh, n0, LD, kb, Bs, wv, lane);
            __syncthreads();
            int qd = lane >> 4;
            bf16x8 af[4], bf[4];
#pragma unroll
            for (int i = 0; i < 4; ++i) af[i] = frag_ld(As, wm + i * 16 + (lane & 15), qd);
#pragma unroll
            for (int j = 0; j < 4; ++j) bf[j] = frag_ld(Bs, wn + j * 16 + (lane & 15), qd);
#pragma unroll
            for (int i = 0; i < 4; ++i)
#pragma unroll
                for (int j = 0; j < 4; ++j)
                    acc[i][j] = __builtin_amdgcn_mfma_f32_16x16x32_bf16(af[i], bf[j], acc[i][j], 0, 0, 0);
            __syncthreads();
        }
        int col = wn + (lane & 15);
        int rb  = wm + ((lane >> 4) << 2);
#pragma unroll
        for (int i = 0; i < 4; ++i)
#pragma unroll
            for (int j = 0; j < 4; ++j)
#pragma unroll
                for (int r = 0; r < 4; ++r)
                    alphas[(size_t)(m0 + rb + i * 16 + r) * LD + n0 + col + j * 16] = acc[i][j][r];
    } else {
        f32x4 acc[2][2];
#pragma unroll
        for (int i = 0; i < 2; ++i)
#pragma unroll
            for (int j = 0; j < 2; ++j) acc[i][j] = (f32x4){0.f, 0.f, 0.f, 0.f};
        for (int kb = 0; kb < LD; kb += 32) {
            stage_tile(Zh, m0, LD, kb, As, wv, lane);
            if (wv < 2) {
                int r = wv * 16 + (lane >> 2);
                int qd = (lane & 3) ^ ((r >> 1) & 3);
                gl_lds16(cwbh + (size_t)r * LD + kb + qd * 8, Bs + wv * 512);
            }
            __syncthreads();
            int qd = lane >> 4;
            bf16x8 af[2], bff[2];
#pragma unroll
            for (int i = 0; i < 2; ++i) af[i] = frag_ld(As, wv * 32 + i * 16 + (lane & 15), qd);
#pragma unroll
            for (int j = 0; j < 2; ++j) bff[j] = frag_ld(Bs, j * 16 + (lane & 15), qd);
#pragma unroll
            for (int i = 0; i < 2; ++i)
#pragma unroll
                for (int j = 0; j < 2; ++j)
                    acc[i][j] = __builtin_amdgcn_mfma_f32_16x16x32_bf16(af[i], bff[j], acc[i][j], 0, 0, 0);
            __syncthreads();
        }
        int col = lane & 15;
        int rb  = (lane >> 4) << 2;
#pragma unroll
        for (int i = 0; i < 2; ++i)
#pragma unroll
            for (int j = 0; j < 2; ++j)
#pragma unroll
                for (int r = 0; r < 4; ++r) {
                    int row = m0 + wv * 32 + i * 16 + rb + r;
                    int cc  = j * 16 + col;
                    logits[(size_t)row * NB + cc] = acc[i][j][r] + cb[cc];
                }
    }
}

// ---------------------------------------------------------------------------
// Fused scan helpers: softmax(logits row) and A-basis column in LDS/registers.
// Block = one (b, chunk); thread = one d.
// ---------------------------------------------------------------------------
__device__ __forceinline__ void scan_prolog(const float* __restrict__ logits,
                                            const float* __restrict__ obs,
                                            const float* __restrict__ Ab,
                                            int bt0, int d,
                                            float (*lg)[NB], float* obs_s, float* abc) {
    int tid = threadIdx.x;
    // load 64x32 logits tile (already includes bias)
    float4* lg4 = (float4*)lg;
    const float4* g4 = (const float4*)(logits + (size_t)bt0 * NB);
    lg4[tid]       = g4[tid];
    lg4[tid + 256] = g4[tid + 256];
    if (tid < CHUNK) obs_s[tid] = obs[bt0 + tid];
    __syncthreads();
    // softmax each row: half-wave (32 lanes) per row, 8 rows per group
    int l = tid & 31, rg = tid >> 5;
#pragma unroll
    for (int j = 0; j < 8; ++j) {
        int row = rg * 8 + j;
        float v = lg[row][l];
        float mx = v;
#pragma unroll
        for (int off = 16; off >= 1; off >>= 1) mx = fmaxf(mx, __shfl_xor(mx, off, 32));
        float e = expf(v - mx);
        float s = e;
#pragma unroll
        for (int off = 16; off >= 1; off >>= 1) s += __shfl_xor(s, off, 32);
        lg[row][l] = e / s;
    }
    __syncthreads();
#pragma unroll
    for (int n = 0; n < NB; ++n) abc[n] = Ab[n * LD + d];
}

// Pass 1: chunk totals
__global__ __launch_bounds__(256) void k_tot(const float* __restrict__ logits,
                                             const float* __restrict__ alphas,
                                             const float* __restrict__ obs,
                                             const float* __restrict__ Ab,
                                             float* __restrict__ totA,
                                             float* __restrict__ totBm,
                                             float* __restrict__ totBv) {
    __shared__ float lg[CHUNK][NB];
    __shared__ float obs_s[CHUNK];
    int d = threadIdx.x;
    int b = blockIdx.x >> 5, ch = blockIdx.x & 31;
    int bt0 = b * T_ + ch * CHUNK;
    float abc[NB];
    scan_prolog(logits, obs, Ab, bt0, d, lg, obs_s, abc);
    float ra = 1.f, rm = 0.f, rv = 0.f;
    for (int i = 0; i < CHUNK; ++i) {
        float av = alphas[(size_t)(bt0 + i) * LD + d];
        float Am = 0.f;
#pragma unroll
        for (int n = 0; n < NB; ++n) Am = fmaf(lg[i][n], abc[n], Am);
        float tt  = obs_s[i];
        float eAm = expf(Am * tt);
        float ieA = 1.f / Am;
        float eBm = (eAm - 1.f) * ieA * av;
        float eBv = 0.5f * (eAm * eAm - 1.f) * ieA + EPS;
        rm = fmaf(eAm, rm, eBm);
        rv = fmaf(eAm * eAm, rv, eBv);
        ra *= eAm;
    }
    int pidx = blockIdx.x * LD + d;
    totA[pidx] = ra; totBm[pidx] = rm; totBv[pidx] = rv;
}

// exclusive prefix over chunks per (b,d)
__global__ void k_chunkpfx(const float* __restrict__ totA, const float* __restrict__ totBm,
                           const float* __restrict__ totBv,
                           float* __restrict__ preA, float* __restrict__ preBm,
                           float* __restrict__ preBv) {
    int d = threadIdx.x;
    int b = blockIdx.x;
    float Pa = 1.f, Pm = 0.f, Pv = 0.f;
    for (int ch = 0; ch < NCH; ++ch) {
        int pidx = (b * NCH + ch) * LD + d;
        preA[pidx] = Pa; preBm[pidx] = Pm; preBv[pidx] = Pv;
        float a = totA[pidx], tm_ = totBm[pidx], tv = totBv[pidx];
        Pm = fmaf(a, Pm, tm_);
        Pv = fmaf(a * a, Pv, tv);
        Pa = a * Pa;
    }
}

// Pass 2: prefix-composed scan, emit bf16 m and s
__global__ __launch_bounds__(256) void k_scan_apply(const float* __restrict__ logits,
                                                    const float* __restrict__ alphas,
                                                    const float* __restrict__ obs,
                                                    const float* __restrict__ Ab,
                                                    const float* __restrict__ preA,
                                                    const float* __restrict__ preBm,
                                                    const float* __restrict__ preBv,
                                                    const float* __restrict__ im0,
                                                    const float* __restrict__ iv0,
                                                    const float* __restrict__ yv,
                                                    unsigned short* __restrict__ Mh,
                                                    unsigned short* __restrict__ Sh) {
    __shared__ float lg[CHUNK][NB];
    __shared__ float obs_s[CHUNK];
    int d = threadIdx.x;
    int b = blockIdx.x >> 5, ch = blockIdx.x & 31;
    int bt0 = b * T_ + ch * CHUNK;
    float abc[NB];
    scan_prolog(logits, obs, Ab, bt0, d, lg, obs_s, abc);
    int pidx = blockIdx.x * LD + d;
    float ga = preA[pidx], gm = preBm[pidx], gv = preBv[pidx];
    float i0 = im0[d], v0 = iv0[d], yvd = yv[d];
    for (int i = 0; i < CHUNK; ++i) {
        size_t idx = (size_t)(bt0 + i) * LD + d;
        float av = alphas[idx];
        float Am = 0.f;
#pragma unroll
        for (int n = 0; n < NB; ++n) Am = fmaf(lg[i][n], abc[n], Am);
        float tt  = obs_s[i];
        float eAm = expf(Am * tt);
        float ieA = 1.f / Am;
        float eBm = (eAm - 1.f) * ieA * av;
        float eBv = 0.5f * (eAm * eAm - 1.f) * ieA + EPS;
        gm = fmaf(eAm, gm, eBm);
        gv = fmaf(eAm * eAm, gv, eBv);
        ga *= eAm;
        float mm = fmaf(ga, i0, gm);
        float vv = fmaf(ga * ga, v0, gv) + yvd;
        Mh[idx] = f2b(mm);
        Sh[idx] = f2b(sqrtf(vv));
    }
}

// ---------------------------------------------------------------------------
// k_ms: grid (BT/128, 4).
//  y<2 : means[:, y*128:...] = [Mh|Zh] @ [GMh|GCh]^T   (K=512)
//  y>=2: stds [:, (y-2)*128:...] = Sh @ GMh^T          (K=256)
// ---------------------------------------------------------------------------
__global__ __launch_bounds__(256) void k_ms(const unsigned short* __restrict__ Mh,
                                            const unsigned short* __restrict__ Zh,
                                            const unsigned short* __restrict__ Sh,
                                            const unsigned short* __restrict__ GMh,
                                            const unsigned short* __restrict__ GCh,
                                            float* __restrict__ means,
                                            float* __restrict__ stds) {
    __shared__ unsigned short As[128 * 32];
    __shared__ unsigned short Bs[128 * 32];
    int tid = threadIdx.x, lane = tid & 63, wv = tid >> 6;
    int m0 = blockIdx.x * 128;
    int y  = blockIdx.y;
    int halves = (y < 2) ? 2 : 1;
    int n0 = (y < 2) ? y * 128 : (y - 2) * 128;
    const unsigned short* A0 = (y < 2) ? Mh : Sh;
    const unsigned short* A1 = Zh;
    const unsigned short* B0 = GMh;
    const unsigned short* B1 = GCh;
    float* C = (y < 2) ? means : stds;
    int wm = (wv & 1) * 64, wn = (wv >> 1) * 64;
    f32x4 acc[4][4];
#pragma unroll
    for (int i = 0; i < 4; ++i)
#pragma unroll
        for (int j = 0; j < 4; ++j) acc[i][j] = (f32x4){0.f, 0.f, 0.f, 0.f};
    for (int h = 0; h < halves; ++h) {
        const unsigned short* A = h ? A1 : A0;
        const unsigned short* B = h ? B1 : B0;
        for (int kb = 0; kb < LD; kb += 32) {
            stage_tile(A, m0, LD, kb, As, wv, lane);
            stage_tile(B, n0, LD, kb, Bs, wv, lane);
            __syncthreads();
            int qd = lane >> 4;
            bf16x8 af[4], bf[4];
#pragma unroll
            for (int i = 0; i < 4; ++i) af[i] = frag_ld(As, wm + i * 16 + (lane & 15), qd);
#pragma unroll
            for (int j = 0; j < 4; ++j) bf[j] = frag_ld(Bs, wn + j * 16 + (lane & 15), qd);
#pragma unroll
            for (int i = 0; i < 4; ++i)
#pragma unroll
                for (int j = 0; j < 4; ++j)
                    acc[i][j] = __builtin_amdgcn_mfma_f32_16x16x32_bf16(af[i], bf[j], acc[i][j], 0, 0, 0);
            __syncthreads();
        }
    }
    int col = wn + (lane & 15);
    int rb  = wm + ((lane >> 4) << 2);
#pragma unroll
    for (int i = 0; i < 4; ++i)
#pragma unroll
        for (int j = 0; j < 4; ++j)
#pragma unroll
            for (int r = 0; r < 4; ++r)
                C[(size_t)(m0 + rb + i * 16 + r) * LD + n0 + col + j * 16] = acc[i][j][r];
}

// ---------------------------------------------------------------------------
extern "C" void kernel_launch(void* const* d_in, const int* in_sizes, int n_in,
                              void* d_out, int out_size, void* d_ws, size_t ws_size,
                              hipStream_t stream) {
    const float* Z   = (const float*)d_in[0];
    const float* obs = (const float*)d_in[1];
    const float* Dm  = (const float*)d_in[2];
    const float* cw  = (const float*)d_in[3];
    const float* cb  = (const float*)d_in[4];
    const float* Ew  = (const float*)d_in[5];
    const float* Bw  = (const float*)d_in[6];
    const float* Cw  = (const float*)d_in[7];
    const float* Mw  = (const float*)d_in[8];
    const float* imp = (const float*)d_in[9];
    const float* ilv = (const float*)d_in[10];
    const float* ylv = (const float*)d_in[11];

    float* out    = (float*)d_out;
    float* means  = out;
    float* stds   = out + (size_t)BT * LD;
    float* alphas = out + (size_t)2 * BT * LD;

    char* ws = (char*)d_ws;
    size_t o = 0;
    unsigned short* Zh   = (unsigned short*)(ws + o); o += (size_t)BT * LD * 2;   // 16MB
    unsigned short* Mh   = (unsigned short*)(ws + o); o += (size_t)BT * LD * 2;   // 16MB
    unsigned short* Sh   = (unsigned short*)(ws + o); o += (size_t)BT * LD * 2;   // 16MB
    float*          logits=(float*)(ws + o);          o += (size_t)BT * NB * 4;   // 4MB
    unsigned short* GMh  = (unsigned short*)(ws + o); o += (size_t)LD * LD * 2;
    unsigned short* GCh  = (unsigned short*)(ws + o); o += (size_t)LD * LD * 2;
    unsigned short* Bwh  = (unsigned short*)(ws + o); o += (size_t)LD * LD * 2;
    unsigned short* cwbh = (unsigned short*)(ws + o); o += (size_t)NB * LD * 2;
    float* Ab    = (float*)(ws + o); o += (size_t)NB * LD * 4;
    float* totA  = (float*)(ws + o); o += (size_t)B_ * NCH * LD * 4;
    float* totBm = (float*)(ws + o); o += (size_t)B_ * NCH * LD * 4;
    float* totBv = (float*)(ws + o); o += (size_t)B_ * NCH * LD * 4;
    float* preA  = (float*)(ws + o); o += (size_t)B_ * NCH * LD * 4;
    float* preBm = (float*)(ws + o); o += (size_t)B_ * NCH * LD * 4;
    float* preBv = (float*)(ws + o); o += (size_t)B_ * NCH * LD * 4;
    float* im0   = (float*)(ws + o); o += LD * 4;
    float* iv0   = (float*)(ws + o); o += LD * 4;
    float* yv    = (float*)(ws + o); o += LD * 4;

    // 1. all precompute
    k_pre<<<dim3(641 + BT * LD / 1024), dim3(256), 0, stream>>>(
        Z, Dm, cw, Ew, Bw, Cw, Mw, imp, ilv, ylv,
        GMh, GCh, cwbh, im0, iv0, yv, Ab, Bwh, Zh);

    // 2. alphas + logits (both straight from Zh)
    k_zb<<<dim3(BT / 128, 3), dim3(256), 0, stream>>>(Zh, Bwh, cwbh, cb, alphas, logits);

    // 3-5. fused softmax/Amat/emap scan (2-pass)
    k_tot<<<dim3(B_ * NCH), dim3(LD), 0, stream>>>(logits, alphas, obs, Ab, totA, totBm, totBv);
    k_chunkpfx<<<dim3(B_), dim3(LD), 0, stream>>>(totA, totBm, totBv, preA, preBm, preBv);
    k_scan_apply<<<dim3(B_ * NCH), dim3(LD), 0, stream>>>(logits, alphas, obs, Ab,
                                                          preA, preBm, preBv,
                                                          im0, iv0, yv, Mh, Sh);

    // 6. means + stds in one launch
    k_ms<<<dim3(BT / 128, 4), dim3(256), 0, stream>>>(Mh, Zh, Sh, GMh, GCh, means, stds);
}

// Round 4
// 244.490 us; speedup vs baseline: 2.2453x; 1.0196x over previous
//
#include <hip/hip_runtime.h>
#include <math.h>

#define EPS 1e-6f

#define B_   16
#define T_   2048
#define LD   256
#define NB   32
#define BT   (B_ * T_)          // 32768
#define NCH  64
#define CHUNK (T_ / NCH)        // 32

typedef short bf16x8 __attribute__((ext_vector_type(8)));
typedef float f32x4  __attribute__((ext_vector_type(4)));

__device__ __forceinline__ unsigned short f2b(float f) {
    unsigned int u = __float_as_uint(f);
    unsigned int r = (u + 0x7fffu + ((u >> 16) & 1u)) >> 16;
    return (unsigned short)r;
}

__device__ __forceinline__ void gl_lds16(const void* g, void* l) {
    __builtin_amdgcn_global_load_lds(
        (const __attribute__((address_space(1))) unsigned int*)g,
        (__attribute__((address_space(3))) unsigned int*)l, 16, 0, 0);
}

// Stage a 128-row x 32-col bf16 tile into LDS [128][32] with quad swizzle:
// physical quad p at row r holds logical quad qd = p ^ ((r>>1)&3).
__device__ __forceinline__ void stage_tile(const unsigned short* __restrict__ src,
                                           int row0, int stride, int kb,
                                           unsigned short* lds, int wv, int lane) {
#pragma unroll
    for (int cc = 0; cc < 2; ++cc) {
        int c = wv * 2 + cc;                 // chunk 0..7, 16 rows each
        int r = c * 16 + (lane >> 2);
        int qd = (lane & 3) ^ ((r >> 1) & 3);
        const unsigned short* g = src + (size_t)(row0 + r) * stride + kb + qd * 8;
        gl_lds16(g, lds + c * 512);          // wave-uniform LDS base; HW adds lane*16B
    }
}

// Stage a 256-row x 32-col tile (16 chunks, 4 per wave)
__device__ __forceinline__ void stage_tile256(const unsigned short* __restrict__ src,
                                              int kb, unsigned short* lds, int wv, int lane) {
#pragma unroll
    for (int cc = 0; cc < 4; ++cc) {
        int c = wv * 4 + cc;
        int r = c * 16 + (lane >> 2);
        int qd = (lane & 3) ^ ((r >> 1) & 3);
        const unsigned short* g = src + (size_t)r * LD + kb + qd * 8;
        gl_lds16(g, lds + c * 512);
    }
}

__device__ __forceinline__ bf16x8 frag_ld(const unsigned short* lds, int row, int qd) {
    int pq = qd ^ ((row >> 1) & 3);
    return *(const bf16x8*)(lds + row * 32 + pq * 8);
}

// ---------------------------------------------------------------------------
// k_pre: ALL precompute in one launch, decoded by blockIdx.x (256 thr/block).
// ---------------------------------------------------------------------------
__global__ __launch_bounds__(256) void k_pre(const float* __restrict__ Z,
                                             const float* __restrict__ Dm,
                                             const float* __restrict__ cw,
                                             const float* __restrict__ Ew,
                                             const float* __restrict__ Bw,
                                             const float* __restrict__ Cw,
                                             const float* __restrict__ Mw,
                                             const float* __restrict__ imp,
                                             const float* __restrict__ ilv,
                                             const float* __restrict__ ylv,
                                             unsigned short* __restrict__ GMh,
                                             unsigned short* __restrict__ GCh,
                                             unsigned short* __restrict__ cwbh,
                                             float* __restrict__ im0,
                                             float* __restrict__ iv0,
                                             float* __restrict__ yv,
                                             float* __restrict__ Ab,
                                             unsigned short* __restrict__ Bwh,
                                             unsigned short* __restrict__ Zh) {
    int bid = blockIdx.x;
    int tid = threadIdx.x;
    if (bid < 544) {
        // small GEMM: out[f][d] = sum_e W[f][e] * E[e][d]
        const float* W; const float* E; unsigned short* out; int d0, f0;
        if (bid < 256)      { W = Mw; E = Ew; out = GMh;  d0 = (bid & 15) * 16; f0 = (bid >> 4) * 16; }
        else if (bid < 512) { W = Cw; E = Ew; out = GCh;  d0 = (bid & 15) * 16; f0 = ((bid - 256) >> 4) * 16; }
        else                { W = cw; E = Bw; out = cwbh; d0 = (bid & 15) * 16; f0 = ((bid - 512) >> 4) * 16; }
        __shared__ float Ws[16][17];
        __shared__ float Es[16][17];
        int tx = tid & 15, ty = tid >> 4;
        float acc = 0.f;
        for (int eb = 0; eb < LD; eb += 16) {
            Ws[ty][tx] = W[(f0 + ty) * LD + eb + tx];
            Es[ty][tx] = E[(eb + ty) * LD + d0 + tx];
            __syncthreads();
#pragma unroll
            for (int k = 0; k < 16; ++k) acc = fmaf(Ws[ty][k], Es[k][tx], acc);
            __syncthreads();
        }
        out[(f0 + ty) * LD + d0 + tx] = f2b(acc);
    } else if (bid < 577) {
        int sub = bid - 544;
        int t = tid;
        if (sub == 0) {
            float sm = 0.f, sv = 0.f;
            for (int k = 0; k < LD; ++k) {
                float e = Ew[k * LD + t];
                sm = fmaf(e, imp[k], sm);
                sv = fmaf(e * e, expf(ilv[k]) + EPS, sv);
            }
            im0[t] = sm;
            iv0[t] = sv;
            yv[t]  = expf(ylv[t]) + EPS;
        } else {
            int n = sub - 1;
            Ab[n * LD + t] = -(expf(Dm[n * LD + t]) + EPS);
        }
    } else if (bid < 641) {
        int i = (bid - 577) * 256 + tid;      // float4 index over 256*256/4
        float4 v = ((const float4*)Bw)[i];
        ((ushort4*)Bwh)[i] = make_ushort4(f2b(v.x), f2b(v.y), f2b(v.z), f2b(v.w));
    } else {
        int i = (bid - 641) * 256 + tid;      // float4 index over BT*LD/4
        float4 v = ((const float4*)Z)[i];
        ((ushort4*)Zh)[i] = make_ushort4(f2b(v.x), f2b(v.y), f2b(v.z), f2b(v.w));
    }
}

// ---------------------------------------------------------------------------
// k_zb: grid (BT/128, 3).
//  y<2 : alphas[:,y*128:(y+1)*128] = Zh @ Bwh^T   (fp32 out)
//  y==2: logits = Zh @ cwbh^T + cb                (fp32 out, N=32)
// ---------------------------------------------------------------------------
__global__ __launch_bounds__(256) void k_zb(const unsigned short* __restrict__ Zh,
                                            const unsigned short* __restrict__ Bwh,
                                            const unsigned short* __restrict__ cwbh,
                                            const float* __restrict__ cb,
                                            float* __restrict__ alphas,
                                            float* __restrict__ logits) {
    __shared__ unsigned short As[128 * 32];
    __shared__ unsigned short Bs[128 * 32];
    int tid = threadIdx.x, lane = tid & 63, wv = tid >> 6;
    int m0 = blockIdx.x * 128;
    int y  = blockIdx.y;
    if (y < 2) {
        int n0 = y * 128;
        int wm = (wv & 1) * 64, wn = (wv >> 1) * 64;
        f32x4 acc[4][4];
#pragma unroll
        for (int i = 0; i < 4; ++i)
#pragma unroll
            for (int j = 0; j < 4; ++j) acc[i][j] = (f32x4){0.f, 0.f, 0.f, 0.f};
        for (int kb = 0; kb < LD; kb += 32) {
            stage_tile(Zh, m0, LD, kb, As, wv, lane);
            stage_tile(Bwh, n0, LD, kb, Bs, wv, lane);
            __syncthreads();
            int qd = lane >> 4;
            bf16x8 af[4], bf[4];
#pragma unroll
            for (int i = 0; i < 4; ++i) af[i] = frag_ld(As, wm + i * 16 + (lane & 15), qd);
#pragma unroll
            for (int j = 0; j < 4; ++j) bf[j] = frag_ld(Bs, wn + j * 16 + (lane & 15), qd);
#pragma unroll
            for (int i = 0; i < 4; ++i)
#pragma unroll
                for (int j = 0; j < 4; ++j)
                    acc[i][j] = __builtin_amdgcn_mfma_f32_16x16x32_bf16(af[i], bf[j], acc[i][j], 0, 0, 0);
            __syncthreads();
        }
        int col = wn + (lane & 15);
        int rb  = wm + ((lane >> 4) << 2);
#pragma unroll
        for (int i = 0; i < 4; ++i)
#pragma unroll
            for (int j = 0; j < 4; ++j)
#pragma unroll
                for (int r = 0; r < 4; ++r)
                    alphas[(size_t)(m0 + rb + i * 16 + r) * LD + n0 + col + j * 16] = acc[i][j][r];
    } else {
        f32x4 acc[2][2];
#pragma unroll
        for (int i = 0; i < 2; ++i)
#pragma unroll
            for (int j = 0; j < 2; ++j) acc[i][j] = (f32x4){0.f, 0.f, 0.f, 0.f};
        for (int kb = 0; kb < LD; kb += 32) {
            stage_tile(Zh, m0, LD, kb, As, wv, lane);
            if (wv < 2) {
                int r = wv * 16 + (lane >> 2);
                int qd = (lane & 3) ^ ((r >> 1) & 3);
                gl_lds16(cwbh + (size_t)r * LD + kb + qd * 8, Bs + wv * 512);
            }
            __syncthreads();
            int qd = lane >> 4;
            bf16x8 af[2], bff[2];
#pragma unroll
            for (int i = 0; i < 2; ++i) af[i] = frag_ld(As, wv * 32 + i * 16 + (lane & 15), qd);
#pragma unroll
            for (int j = 0; j < 2; ++j) bff[j] = frag_ld(Bs, j * 16 + (lane & 15), qd);
#pragma unroll
            for (int i = 0; i < 2; ++i)
#pragma unroll
                for (int j = 0; j < 2; ++j)
                    acc[i][j] = __builtin_amdgcn_mfma_f32_16x16x32_bf16(af[i], bff[j], acc[i][j], 0, 0, 0);
            __syncthreads();
        }
        int col = lane & 15;
        int rb  = (lane >> 4) << 2;
#pragma unroll
        for (int i = 0; i < 2; ++i)
#pragma unroll
            for (int j = 0; j < 2; ++j)
#pragma unroll
                for (int r = 0; r < 4; ++r) {
                    int row = m0 + wv * 32 + i * 16 + rb + r;
                    int cc  = j * 16 + col;
                    logits[(size_t)row * NB + cc] = acc[i][j][r] + cb[cc];
                }
    }
}

// ---------------------------------------------------------------------------
// scan prolog: load CHUNK x NB logits tile, softmax in place, load Ab column.
// ---------------------------------------------------------------------------
__device__ __forceinline__ void scan_prolog(const float* __restrict__ logits,
                                            const float* __restrict__ obs,
                                            const float* __restrict__ Ab,
                                            int bt0, int d,
                                            float (*lg)[NB], float* obs_s, float* abc) {
    int tid = threadIdx.x;
    // CHUNK*NB = 1024 floats = 256 float4
    float4* lg4 = (float4*)lg;
    const float4* g4 = (const float4*)(logits + (size_t)bt0 * NB);
    lg4[tid] = g4[tid];
    if (tid < CHUNK) obs_s[tid] = obs[bt0 + tid];
    __syncthreads();
    int l = tid & 31, rg = tid >> 5;
#pragma unroll
    for (int j = 0; j < CHUNK / 8; ++j) {
        int row = rg * (CHUNK / 8) + j;
        float v = lg[row][l];
        float mx = v;
#pragma unroll
        for (int off = 16; off >= 1; off >>= 1) mx = fmaxf(mx, __shfl_xor(mx, off, 32));
        float e = expf(v - mx);
        float s = e;
#pragma unroll
        for (int off = 16; off >= 1; off >>= 1) s += __shfl_xor(s, off, 32);
        lg[row][l] = e / s;
    }
    __syncthreads();
#pragma unroll
    for (int n = 0; n < NB; ++n) abc[n] = Ab[n * LD + d];
}

// ---------------------------------------------------------------------------
// Pass 1: chunk totals (recompute softmax/Amat/emap on the fly)
// ---------------------------------------------------------------------------
__global__ __launch_bounds__(256) void k_tot(const float* __restrict__ logits,
                                             const float* __restrict__ alphas,
                                             const float* __restrict__ obs,
                                             const float* __restrict__ Ab,
                                             float* __restrict__ totA,
                                             float* __restrict__ totBm,
                                             float* __restrict__ totBv) {
    __shared__ float lg[CHUNK][NB];
    __shared__ float obs_s[CHUNK];
    int d = threadIdx.x;
    int bt0 = blockIdx.x * CHUNK;
    float abc[NB];
    scan_prolog(logits, obs, Ab, bt0, d, lg, obs_s, abc);
    float ra = 1.f, rm = 0.f, rv = 0.f;
    for (int i = 0; i < CHUNK; ++i) {
        float av = alphas[(size_t)(bt0 + i) * LD + d];
        float Am = 0.f;
#pragma unroll
        for (int n = 0; n < NB; ++n) Am = fmaf(lg[i][n], abc[n], Am);
        float tt  = obs_s[i];
        float eAm = expf(Am * tt);
        float ieA = 1.f / Am;
        float eBm = (eAm - 1.f) * ieA * av;
        float eBv = 0.5f * (eAm * eAm - 1.f) * ieA + EPS;
        rm = fmaf(eAm, rm, eBm);
        rv = fmaf(eAm * eAm, rv, eBv);
        ra *= eAm;
    }
    int pidx = blockIdx.x * LD + d;
    totA[pidx] = ra; totBm[pidx] = rm; totBv[pidx] = rv;
}

// exclusive prefix over chunks per (b,d)
__global__ void k_chunkpfx(const float* __restrict__ totA, const float* __restrict__ totBm,
                           const float* __restrict__ totBv,
                           float* __restrict__ preA, float* __restrict__ preBm,
                           float* __restrict__ preBv) {
    int d = threadIdx.x;
    int b = blockIdx.x;
    float Pa = 1.f, Pm = 0.f, Pv = 0.f;
    for (int ch = 0; ch < NCH; ++ch) {
        int pidx = (b * NCH + ch) * LD + d;
        preA[pidx] = Pa; preBm[pidx] = Pm; preBv[pidx] = Pv;
        float a = totA[pidx], tm_ = totBm[pidx], tv = totBv[pidx];
        Pm = fmaf(a, Pm, tm_);
        Pv = fmaf(a * a, Pv, tv);
        Pa = a * Pa;
    }
}

// ---------------------------------------------------------------------------
// k_sms: fused pass 2 + output GEMMs.  One block per (b,chunk):
//   scan -> m,s (bf16, swizzled) in LDS -> MFMA:
//     stds  = s @ GM^T ; means = m @ GM^T + Z @ GC^T
// LDS: Ms 16KB | Ss 16KB (reused for Z slices) | Bs 16KB (lg/obs alias in Bs)
// ---------------------------------------------------------------------------
__global__ __launch_bounds__(256) void k_sms(const float* __restrict__ logits,
                                             const float* __restrict__ alphas,
                                             const float* __restrict__ obs,
                                             const float* __restrict__ Ab,
                                             const float* __restrict__ preA,
                                             const float* __restrict__ preBm,
                                             const float* __restrict__ preBv,
                                             const float* __restrict__ im0,
                                             const float* __restrict__ iv0,
                                             const float* __restrict__ yv,
                                             const unsigned short* __restrict__ Zh,
                                             const unsigned short* __restrict__ GMh,
                                             const unsigned short* __restrict__ GCh,
                                             float* __restrict__ means,
                                             float* __restrict__ stds) {
    __shared__ unsigned short Ms[CHUNK * LD];   // 16KB, [dchunk][row][32] swizzled
    __shared__ unsigned short Ss[CHUNK * LD];   // 16KB, same; reused for Z slices
    __shared__ unsigned short Bs[256 * 32];     // 16KB B-tile staging
    float (*lg)[NB] = (float(*)[NB])Bs;         // 4KB alias (scan phase only)
    float* obs_s = (float*)(Bs + 2048 + 2048);  // +8KB into Bs region

    int tid = threadIdx.x, lane = tid & 63, wv = tid >> 6;
    int d = tid;
    int bt0 = blockIdx.x * CHUNK;
    float abc[NB];
    scan_prolog(logits, obs, Ab, bt0, d, lg, obs_s, abc);

    int pidx = blockIdx.x * LD + d;
    float ga = preA[pidx], gm = preBm[pidx], gv = preBv[pidx];
    float i0 = im0[d], v0 = iv0[d], yvd = yv[d];
    int dc = d >> 5, q = (d & 31) >> 3, jj = d & 7;
    for (int i = 0; i < CHUNK; ++i) {
        float av = alphas[(size_t)(bt0 + i) * LD + d];
        float Am = 0.f;
#pragma unroll
        for (int n = 0; n < NB; ++n) Am = fmaf(lg[i][n], abc[n], Am);
        float tt  = obs_s[i];
        float eAm = expf(Am * tt);
        float ieA = 1.f / Am;
        float eBm = (eAm - 1.f) * ieA * av;
        float eBv = 0.5f * (eAm * eAm - 1.f) * ieA + EPS;
        gm = fmaf(eAm, gm, eBm);
        gv = fmaf(eAm * eAm, gv, eBv);
        ga *= eAm;
        float mm = fmaf(ga, i0, gm);
        float vv = fmaf(ga * ga, v0, gv) + yvd;
        int pq = q ^ ((i >> 1) & 3);
        int a = dc * (CHUNK * 32) + i * 32 + pq * 8 + jj;
        Ms[a] = f2b(mm);
        Ss[a] = f2b(sqrtf(vv));
    }
    __syncthreads();

    // ---- MFMA phase 1: B = GM, A = Ms (means) and Ss (stds) ----
    f32x4 accm[2][4], accs[2][4];
#pragma unroll
    for (int i = 0; i < 2; ++i)
#pragma unroll
        for (int j = 0; j < 4; ++j) {
            accm[i][j] = (f32x4){0.f, 0.f, 0.f, 0.f};
            accs[i][j] = (f32x4){0.f, 0.f, 0.f, 0.f};
        }
    int qd = lane >> 4, mr = lane & 15;
    for (int kc = 0; kc < 8; ++kc) {
        stage_tile256(GMh, kc * 32, Bs, wv, lane);
        __syncthreads();
        bf16x8 am[2], as[2], bfr[4];
#pragma unroll
        for (int i = 0; i < 2; ++i) {
            int row = i * 16 + mr;
            int pq = qd ^ ((row >> 1) & 3);
            am[i] = *(const bf16x8*)(Ms + kc * (CHUNK * 32) + row * 32 + pq * 8);
            as[i] = *(const bf16x8*)(Ss + kc * (CHUNK * 32) + row * 32 + pq * 8);
        }
#pragma unroll
        for (int j = 0; j < 4; ++j) bfr[j] = frag_ld(Bs, wv * 64 + j * 16 + mr, qd);
#pragma unroll
        for (int i = 0; i < 2; ++i)
#pragma unroll
            for (int j = 0; j < 4; ++j) {
                accm[i][j] = __builtin_amdgcn_mfma_f32_16x16x32_bf16(am[i], bfr[j], accm[i][j], 0, 0, 0);
                accs[i][j] = __builtin_amdgcn_mfma_f32_16x16x32_bf16(as[i], bfr[j], accs[i][j], 0, 0, 0);
            }
        __syncthreads();
    }

    // ---- MFMA phase 2: B = GC, A = Z slices (staged into Ss region) ----
    for (int kc = 0; kc < 8; ++kc) {
        stage_tile256(GCh, kc * 32, Bs, wv, lane);
        if (wv < 2) {
            int r = wv * 16 + (lane >> 2);
            int qz = (lane & 3) ^ ((r >> 1) & 3);
            gl_lds16(Zh + (size_t)(bt0 + r) * LD + kc * 32 + qz * 8, Ss + wv * 512);
        }
        __syncthreads();
        bf16x8 az[2], bfr[4];
#pragma unroll
        for (int i = 0; i < 2; ++i) az[i] = frag_ld(Ss, i * 16 + mr, qd);
#pragma unroll
        for (int j = 0; j < 4; ++j) bfr[j] = frag_ld(Bs, wv * 64 + j * 16 + mr, qd);
#pragma unroll
        for (int i = 0; i < 2; ++i)
#pragma unroll
            for (int j = 0; j < 4; ++j)
                accm[i][j] = __builtin_amdgcn_mfma_f32_16x16x32_bf16(az[i], bfr[j], accm[i][j], 0, 0, 0);
        __syncthreads();
    }

    // ---- epilogue ----
    int col0 = wv * 64 + mr;
    int rb   = (lane >> 4) << 2;
#pragma unroll
    for (int i = 0; i < 2; ++i)
#pragma unroll
        for (int j = 0; j < 4; ++j)
#pragma unroll
            for (int r = 0; r < 4; ++r) {
                size_t off = (size_t)(bt0 + i * 16 + rb + r) * LD + col0 + j * 16;
                means[off] = accm[i][j][r];
                stds[off]  = accs[i][j][r];
            }
}

// ---------------------------------------------------------------------------
extern "C" void kernel_launch(void* const* d_in, const int* in_sizes, int n_in,
                              void* d_out, int out_size, void* d_ws, size_t ws_size,
                              hipStream_t stream) {
    const float* Z   = (const float*)d_in[0];
    const float* obs = (const float*)d_in[1];
    const float* Dm  = (const float*)d_in[2];
    const float* cw  = (const float*)d_in[3];
    const float* cb  = (const float*)d_in[4];
    const float* Ew  = (const float*)d_in[5];
    const float* Bw  = (const float*)d_in[6];
    const float* Cw  = (const float*)d_in[7];
    const float* Mw  = (const float*)d_in[8];
    const float* imp = (const float*)d_in[9];
    const float* ilv = (const float*)d_in[10];
    const float* ylv = (const float*)d_in[11];

    float* out    = (float*)d_out;
    float* means  = out;
    float* stds   = out + (size_t)BT * LD;
    float* alphas = out + (size_t)2 * BT * LD;

    char* ws = (char*)d_ws;
    size_t o = 0;
    unsigned short* Zh   = (unsigned short*)(ws + o); o += (size_t)BT * LD * 2;   // 16MB
    float*          logits=(float*)(ws + o);          o += (size_t)BT * NB * 4;   // 4MB
    unsigned short* GMh  = (unsigned short*)(ws + o); o += (size_t)LD * LD * 2;
    unsigned short* GCh  = (unsigned short*)(ws + o); o += (size_t)LD * LD * 2;
    unsigned short* Bwh  = (unsigned short*)(ws + o); o += (size_t)LD * LD * 2;
    unsigned short* cwbh = (unsigned short*)(ws + o); o += (size_t)NB * LD * 2;
    float* Ab    = (float*)(ws + o); o += (size_t)NB * LD * 4;
    float* totA  = (float*)(ws + o); o += (size_t)B_ * NCH * LD * 4;
    float* totBm = (float*)(ws + o); o += (size_t)B_ * NCH * LD * 4;
    float* totBv = (float*)(ws + o); o += (size_t)B_ * NCH * LD * 4;
    float* preA  = (float*)(ws + o); o += (size_t)B_ * NCH * LD * 4;
    float* preBm = (float*)(ws + o); o += (size_t)B_ * NCH * LD * 4;
    float* preBv = (float*)(ws + o); o += (size_t)B_ * NCH * LD * 4;
    float* im0   = (float*)(ws + o); o += LD * 4;
    float* iv0   = (float*)(ws + o); o += LD * 4;
    float* yv    = (float*)(ws + o); o += LD * 4;

    // 1. all precompute
    k_pre<<<dim3(641 + BT * LD / 1024), dim3(256), 0, stream>>>(
        Z, Dm, cw, Ew, Bw, Cw, Mw, imp, ilv, ylv,
        GMh, GCh, cwbh, im0, iv0, yv, Ab, Bwh, Zh);

    // 2. alphas + logits (both straight from Zh)
    k_zb<<<dim3(BT / 128, 3), dim3(256), 0, stream>>>(Zh, Bwh, cwbh, cb, alphas, logits);

    // 3-4. chunk totals + prefix
    k_tot<<<dim3(B_ * NCH), dim3(LD), 0, stream>>>(logits, alphas, obs, Ab, totA, totBm, totBv);
    k_chunkpfx<<<dim3(B_), dim3(LD), 0, stream>>>(totA, totBm, totBv, preA, preBm, preBv);

    // 5. fused scan + means/stds GEMMs
    k_sms<<<dim3(B_ * NCH), dim3(256), 0, stream>>>(logits, alphas, obs, Ab,
                                                    preA, preBm, preBv,
                                                    im0, iv0, yv,
                                                    Zh, GMh, GCh, means, stds);
}